// Round 9
// baseline (294.920 us; speedup 1.0000x reference)
//
#include <hip/hip_runtime.h>
#include <hip/hip_bf16.h>

typedef unsigned short u16;
typedef unsigned char u8;
typedef float f32x4 __attribute__((ext_vector_type(4)));
typedef int int4v __attribute__((ext_vector_type(4)));
typedef int int8v __attribute__((ext_vector_type(8)));

#define B_ROWS 8192
#define D_DIM  1024
#define FP8_SCALE 16.0f          // store x*16 in e4m3; acc = 256 * s_true
#define ACC_UNSCALE (1.0f/256.0f)

// ---------------------------------------------------------------------------
// Workspace layout (bytes):
//   [0,      32768)   ppq[8192]   per-row MSE(q) partial
//   [32768,  65536)   ppp[8192]   per-row MSE(p) partial
//   [65536,  98304)   ppd[8192]   per-row diag cosine (exact fp32)
//   [98304,  98816)   bpart[32][4] per-reduce-block partials
//   [131072, +4MiB)   gpart[128][8192]  per-64-col-slice row exp-sum partials
//   [+4MiB,  +8MiB)   qn fp8 [8192][1024]   (x16 pre-scaled e4m3)
//   [+8MiB,  ...)     pn fp8 [8192][1024]
// ---------------------------------------------------------------------------

// ---------------------------------------------------------------------------
// Kernel 1: one WAVE per row — butterfly reduce, fp8 quantize. (unchanged)
// ---------------------------------------------------------------------------
__global__ void __launch_bounds__(256) prep_kernel(
    const float* __restrict__ sq, const float* __restrict__ sp,
    const float* __restrict__ tq, const float* __restrict__ tp,
    int* __restrict__ qn, int* __restrict__ pn,
    float* __restrict__ ppq, float* __restrict__ ppp, float* __restrict__ ppd)
{
    const int wave = threadIdx.x >> 6;
    const int l    = threadIdx.x & 63;
    const int r    = blockIdx.x * 4 + wave;
    const size_t rb4 = (size_t)r * (D_DIM / 4);

    const float4* Q4 = (const float4*)sq + rb4;
    const float4* P4 = (const float4*)sp + rb4;
    const float4* A4 = (const float4*)tq + rb4;
    const float4* B4 = (const float4*)tp + rb4;

    float4 qv[4], pv[4];
    float sq2 = 0.f, sp2 = 0.f, dq = 0.f, dp = 0.f, qp = 0.f;
    #pragma unroll
    for (int j = 0; j < 4; ++j) {
        const int idx = j * 64 + l;
        float4 q = Q4[idx], p = P4[idx], a = A4[idx], b = B4[idx];
        qv[j] = q; pv[j] = p;
        sq2 += q.x*q.x + q.y*q.y + q.z*q.z + q.w*q.w;
        sp2 += p.x*p.x + p.y*p.y + p.z*p.z + p.w*p.w;
        float dx = q.x-a.x, dy = q.y-a.y, dz = q.z-a.z, dw = q.w-a.w;
        dq += dx*dx + dy*dy + dz*dz + dw*dw;
        dx = p.x-b.x; dy = p.y-b.y; dz = p.z-b.z; dw = p.w-b.w;
        dp += dx*dx + dy*dy + dz*dz + dw*dw;
        qp += q.x*p.x + q.y*p.y + q.z*p.z + q.w*p.w;
    }

    #pragma unroll
    for (int m = 1; m <= 32; m <<= 1) {
        sq2 += __shfl_xor(sq2, m);
        sp2 += __shfl_xor(sp2, m);
        dq  += __shfl_xor(dq, m);
        dp  += __shfl_xor(dp, m);
        qp  += __shfl_xor(qp, m);
    }

    const float rq = 1.0f / fmaxf(sqrtf(sq2), 1e-8f);
    const float rp = 1.0f / fmaxf(sqrtf(sp2), 1e-8f);

    if (l == 0) {
        ppq[r] = dq;
        ppp[r] = dp;
        ppd[r] = qp * rq * rp;
    }

    const float fq = rq * FP8_SCALE;
    const float fp = rp * FP8_SCALE;
    int* qrow = qn + (size_t)r * (D_DIM / 4);
    int* prow = pn + (size_t)r * (D_DIM / 4);
    #pragma unroll
    for (int j = 0; j < 4; ++j) {
        const int idx = j * 64 + l;
        int pk = __builtin_amdgcn_cvt_pk_fp8_f32(qv[j].x * fq, qv[j].y * fq, 0, false);
        pk     = __builtin_amdgcn_cvt_pk_fp8_f32(qv[j].z * fq, qv[j].w * fq, pk, true);
        qrow[idx] = pk;
        pk = __builtin_amdgcn_cvt_pk_fp8_f32(pv[j].x * fp, pv[j].y * fp, 0, false);
        pk = __builtin_amdgcn_cvt_pk_fp8_f32(pv[j].z * fp, pv[j].w * fp, pk, true);
        prow[idx] = pk;
    }
}

// ---------------------------------------------------------------------------
// Kernel 2: S = Qn @ Pn^T via MX-scaled fp8 MFMA 16x16x128.
// *** r8 structure (128x128 tile, 4 waves 2x2, 3 blocks/CU cross-block
//     overlap) + B DIRECT FROM L2 (r4 mechanism, now in the right regime) ***
//
// r8 accounting: DS floor 55 us (8192 b128/CU x 16 cy) > MFMA floor 29 us;
// measured 76 us = 72% of the DS roofline.  DS volume is the wall, and the
// register file forbids bigger patches.  Fix: drop B from LDS entirely —
// each wave loads its 4 B-fragments straight from global/L2 (lane-local
// bytes, 8 dwordx4/step).  DS reads/step halve (32 -> 16 per block), new
// floor max(DS 27, MFMA 29) ~ 30 us.  r4 proved FETCH_SIZE stays ~37 MB
// (L2/L3 absorb B traffic); r4's regression was lockstep latency exposure,
// which the 3-blocks/CU overlap covers.
//
// Per step t: issue bf(t) (8 vmem) -> vmcnt(8) retires A-staging(t), bf
// stays in flight -> barrier -> 8 ds_read_b128 af -> lgkm(0) -> barrier
// (A-buf WAR safe) -> restage A(t+1) (4 gload_lds) -> vmcnt(4) retires bf
// -> 16 MFMA under setprio.  Fragment bytes identical -> output
// bit-identical to r8.  Regs ~ acc64+af32+bf32+addr -> 3 blocks/CU.
// ---------------------------------------------------------------------------
union Frag { int8v v8; struct { int4v lo, hi; } h; };

__global__ void __launch_bounds__(256, 3) gemm_rowsum_kernel(
    const u8* __restrict__ Q, const u8* __restrict__ P,
    float* __restrict__ gpart)
{
    __shared__ u8 smA[128 * 128];   // 16 KiB, row stride 128 B (A only)

    const int tid  = threadIdx.x;
    const int wave = tid >> 6;         // 0..3
    const int lane = tid & 63;
    const int wm   = wave >> 1;        // 0..1 : 64-row half of the tile
    const int wn   = wave & 1;         // 0..1 : 64-col half of the tile
    const int bm   = blockIdx.y;
    const int bn   = blockIdx.x;

    // A staging: one STAGE call (256 threads) covers 32 rows x 128 B.
    // LDS written linearly; 16B-chunk XOR swizzle (r5/r8 scheme) applied on
    // the GLOBAL source address; read side XORs with row&7.
    const int srow   = tid >> 3;                    // 0..31 within a call
    const int schunk = (tid & 7) ^ (srow & 7);      // pre-swizzled 16B chunk
    const u8* Ag = Q + (size_t)(bm * 128 + srow) * D_DIM + schunk * 16;
    const int ldsw = wave * 1024;                   // wave's 8-row sub-chunk

#define STAGE_A(rbase, k0)                                                     \
    __builtin_amdgcn_global_load_lds(                                          \
        (const __attribute__((address_space(1))) void*)(Ag + (size_t)(rbase) * D_DIM + (k0)), \
        (__attribute__((address_space(3))) void*)(smA + (rbase) * 128 + ldsw), 16, 0, 0)

// 4 vmem issues per call, covering the full 128-row A tile
#define STAGE_ALL(k0)                                                          \
    STAGE_A(0, k0); STAGE_A(32, k0); STAGE_A(64, k0); STAGE_A(96, k0);

    // A fragment addressing (r5 swizzle):
    // A frag (mi): row = wm*64 + mi*16 + rw; k-chunks 2q,2q+1 at slots ^r7
    const int quad = lane >> 4;
    const int rw   = lane & 15;
    const int r7   = lane & 7;
    const int off_lo = ((2 * quad) ^ r7) * 16;
    const int off_hi = ((2 * quad + 1) ^ r7) * 16;
    const int arow_base = (wm * 64 + rw) * 128;     // + mi*2048

    // B direct-load base: lane l covers B-row (bn*128 + wn*64 + ni*16 + rw),
    // k-bytes quad*32 .. +32 of k-chunk t*128.  Same bytes as the old LDS
    // path -> bit-identical MFMA inputs.
    const u8* Bd = P + (size_t)(bn * 128 + wn * 64 + rw) * D_DIM + quad * 32;

    f32x4 acc[4][4];
    #pragma unroll
    for (int i = 0; i < 4; ++i)
        #pragma unroll
        for (int j = 0; j < 4; ++j)
            acc[i][j] = (f32x4){0.f, 0.f, 0.f, 0.f};

    // prologue: stage A(0)
    STAGE_ALL(0)

#define SB0 __builtin_amdgcn_sched_barrier(0);

#define MFMA1(mi, ni)                                                          \
    acc[mi][ni] = __builtin_amdgcn_mfma_scale_f32_16x16x128_f8f6f4(            \
        af[mi].v8, bf[ni].v8, acc[mi][ni],                                     \
        0, 0, 0, 0x7f7f7f7f, 0, 0x7f7f7f7f);

#define KSTEP(t, DO_NEXT, VMN)                                                 \
  {                                                                            \
    Frag af[4], bf[4];                                                         \
    /* bf(t) from L2 into regs (latency hides under barrier + ds_reads) */     \
    _Pragma("unroll")                                                          \
    for (int ni = 0; ni < 4; ++ni) {                                           \
      bf[ni].h.lo = *(const int4v*)(Bd + (size_t)ni * 16 * D_DIM + (t) * 128);        \
      bf[ni].h.hi = *(const int4v*)(Bd + (size_t)ni * 16 * D_DIM + (t) * 128 + 16);   \
    }                                                                          \
    /* retire A-staging(t); keep the 8 bf loads in flight */                   \
    asm volatile("s_waitcnt vmcnt(8)" ::: "memory");                           \
    __builtin_amdgcn_s_barrier();                                              \
    SB0                                                                        \
    /* 8 b128 A-reads: lo group then hi group */                               \
    _Pragma("unroll")                                                          \
    for (int mi = 0; mi < 4; ++mi)                                             \
      af[mi].h.lo = *(const int4v*)(smA + arow_base + mi * 2048 + off_lo);     \
    SB0                                                                        \
    _Pragma("unroll")                                                          \
    for (int mi = 0; mi < 4; ++mi)                                             \
      af[mi].h.hi = *(const int4v*)(smA + arow_base + mi * 2048 + off_hi);     \
    asm volatile("s_waitcnt lgkmcnt(0)" ::: "memory");                         \
    SB0                                                                        \
    __builtin_amdgcn_s_barrier();   /* all waves done reading -> WAR safe */   \
    SB0                                                                        \
    /* restage A for t+1 (async), then wait bf, then 16 MFMAs */               \
    if (DO_NEXT) { STAGE_ALL(((t) + 1) * 128) }                                \
    asm volatile("s_waitcnt vmcnt(" #VMN ")" ::: "memory");                    \
    SB0                                                                        \
    __builtin_amdgcn_s_setprio(1);                                             \
    MFMA1(0, 0) MFMA1(0, 1) MFMA1(1, 0) MFMA1(1, 1)                            \
    MFMA1(0, 2) MFMA1(0, 3) MFMA1(1, 2) MFMA1(1, 3)                            \
    MFMA1(2, 0) MFMA1(2, 1) MFMA1(3, 0) MFMA1(3, 1)                            \
    MFMA1(2, 2) MFMA1(2, 3) MFMA1(3, 2) MFMA1(3, 3)                            \
    __builtin_amdgcn_s_setprio(0);                                             \
  }

    KSTEP(0, true,  4)
    KSTEP(1, true,  4)
    KSTEP(2, true,  4)
    KSTEP(3, true,  4)
    KSTEP(4, true,  4)
    KSTEP(5, true,  4)
    KSTEP(6, true,  4)
    KSTEP(7, false, 0)

#undef KSTEP
#undef MFMA1
#undef SB0
#undef STAGE_ALL
#undef STAGE_A

    // epilogue: per-row sum of exp over this wave's 64 columns.
    // C/D layout (shape-determined): col = lane&15, row = quad*4 + reg
    float esum[4][4];
    #pragma unroll
    for (int mi = 0; mi < 4; ++mi)
        #pragma unroll
        for (int r = 0; r < 4; ++r) {
            float s = 0.f;
            #pragma unroll
            for (int ni = 0; ni < 4; ++ni)
                s += __expf(acc[mi][ni][r] * ACC_UNSCALE);
            esum[mi][r] = s;
        }
    #pragma unroll
    for (int m = 1; m <= 8; m <<= 1)
        #pragma unroll
        for (int mi = 0; mi < 4; ++mi)
            #pragma unroll
            for (int r = 0; r < 4; ++r)
                esum[mi][r] += __shfl_xor(esum[mi][r], m);

    // slice index = global_col / 64 = bn*2 + wn
    if (rw == 0) {
        float* dst = gpart + (size_t)(bn * 2 + wn) * B_ROWS
                   + bm * 128 + wm * 64;
        #pragma unroll
        for (int mi = 0; mi < 4; ++mi)
            #pragma unroll
            for (int r = 0; r < 4; ++r)
                dst[mi * 16 + quad * 4 + r] = esum[mi][r];
    }
}

// ---------------------------------------------------------------------------
// Kernel 3: per-row sum of 128 gpart slices -> log; fold in the three
// pp-array reductions; one float4 partial per block. (unchanged)
// ---------------------------------------------------------------------------
__global__ void __launch_bounds__(256) reduce_kernel(
    const float* __restrict__ gpart,
    const float* __restrict__ ppq, const float* __restrict__ ppp,
    const float* __restrict__ ppd, float4* __restrict__ bpart)
{
    const int t = threadIdx.x;
    const int r = blockIdx.x * 256 + t;
    float s = 0.f;
    #pragma unroll 8
    for (int j = 0; j < 128; ++j) s += gpart[(size_t)j * B_ROWS + r];
    float ls = logf(s);
    float v2 = ppq[r], v3 = ppp[r], v4 = ppd[r];
    #pragma unroll
    for (int m = 1; m <= 32; m <<= 1) {
        ls += __shfl_xor(ls, m);
        v2 += __shfl_xor(v2, m);
        v3 += __shfl_xor(v3, m);
        v4 += __shfl_xor(v4, m);
    }
    __shared__ float red[4][4];
    if ((t & 63) == 0) {
        red[t >> 6][0] = ls; red[t >> 6][1] = v2;
        red[t >> 6][2] = v3; red[t >> 6][3] = v4;
    }
    __syncthreads();
    if (t == 0) {
        float4 o;
        o.x = red[0][0] + red[1][0] + red[2][0] + red[3][0];
        o.y = red[0][1] + red[1][1] + red[2][1] + red[3][1];
        o.z = red[0][2] + red[1][2] + red[2][2] + red[3][2];
        o.w = red[0][3] + red[1][3] + red[2][3] + red[3][3];
        bpart[blockIdx.x] = o;
    }
}

// ---------------------------------------------------------------------------
// Kernel 4: final scalar combine (1 wave, 32 float4 partials) (unchanged)
// ---------------------------------------------------------------------------
__global__ void __launch_bounds__(64) finalize_kernel(
    const float4* __restrict__ bpart, float* __restrict__ out)
{
    const int t = threadIdx.x;
    float4 v = (t < 32) ? bpart[t] : (float4){0.f, 0.f, 0.f, 0.f};
    #pragma unroll
    for (int m = 1; m <= 16; m <<= 1) {
        v.x += __shfl_xor(v.x, m);
        v.y += __shfl_xor(v.y, m);
        v.z += __shfl_xor(v.z, m);
        v.w += __shfl_xor(v.w, m);
    }
    if (t == 0) {
        const float inv_bd = 1.0f / ((float)B_ROWS * (float)D_DIM);
        float distill   = 0.5f * (v.y + v.z) * inv_bd;
        float retrieval = (v.x - v.w) / (float)B_ROWS;
        out[0] = 0.5f * distill + 0.5f * retrieval;
    }
}

extern "C" void kernel_launch(void* const* d_in, const int* in_sizes, int n_in,
                              void* d_out, int out_size, void* d_ws, size_t ws_size,
                              hipStream_t stream) {
    const float* sq = (const float*)d_in[0];
    const float* sp = (const float*)d_in[1];
    const float* tq = (const float*)d_in[2];
    const float* tp = (const float*)d_in[3];

    char* ws = (char*)d_ws;
    float*  ppq   = (float*)(ws);
    float*  ppp   = (float*)(ws + 32768);
    float*  ppd   = (float*)(ws + 65536);
    float4* bpart = (float4*)(ws + 98304);
    float*  gpart = (float*)(ws + 131072);                        // 4 MiB
    int*    qn    = (int*)(ws + 131072 + (size_t)128 * B_ROWS * 4);
    int*    pn    = (int*)((char*)qn + (size_t)B_ROWS * D_DIM);

    prep_kernel<<<B_ROWS / 4, 256, 0, stream>>>(sq, sp, tq, tp, qn, pn, ppq, ppp, ppd);
    gemm_rowsum_kernel<<<dim3(64, 64), 256, 0, stream>>>((const u8*)qn, (const u8*)pn, gpart);
    reduce_kernel<<<32, 256, 0, stream>>>(gpart, ppq, ppp, ppd, bpart);
    finalize_kernel<<<1, 64, 0, stream>>>(bpart, (float*)d_out);
}

// Round 10
// 233.522 us; speedup vs baseline: 1.2629x; 1.2629x over previous
//
#include <hip/hip_runtime.h>
#include <hip/hip_bf16.h>

typedef unsigned short u16;
typedef unsigned char u8;
typedef float f32x4 __attribute__((ext_vector_type(4)));
typedef int int4v __attribute__((ext_vector_type(4)));
typedef int int8v __attribute__((ext_vector_type(8)));

#define B_ROWS 8192
#define D_DIM  1024
#define FP8_SCALE 16.0f          // store x*16 in e4m3; acc = 256 * s_true
#define ACC_UNSCALE (1.0f/256.0f)

// ---------------------------------------------------------------------------
// Workspace layout (bytes):
//   [0,      32768)   ppq[8192]   per-row MSE(q) partial
//   [32768,  65536)   ppp[8192]   per-row MSE(p) partial
//   [65536,  98304)   ppd[8192]   per-row diag cosine (exact fp32)
//   [98304,  98816)   bpart[32][4] per-reduce-block partials
//   [131072, +4MiB)   gpart[128][8192]  per-64-col-slice row exp-sum partials
//   [+4MiB,  +8MiB)   qn fp8 [8192][1024]   (x16 pre-scaled e4m3)
//   [+8MiB,  ...)     pn fp8 [8192][1024]
// ---------------------------------------------------------------------------

// ---------------------------------------------------------------------------
// Kernel 1: one WAVE per row — butterfly reduce, fp8 quantize. (unchanged)
// ---------------------------------------------------------------------------
__global__ void __launch_bounds__(256) prep_kernel(
    const float* __restrict__ sq, const float* __restrict__ sp,
    const float* __restrict__ tq, const float* __restrict__ tp,
    int* __restrict__ qn, int* __restrict__ pn,
    float* __restrict__ ppq, float* __restrict__ ppp, float* __restrict__ ppd)
{
    const int wave = threadIdx.x >> 6;
    const int l    = threadIdx.x & 63;
    const int r    = blockIdx.x * 4 + wave;
    const size_t rb4 = (size_t)r * (D_DIM / 4);

    const float4* Q4 = (const float4*)sq + rb4;
    const float4* P4 = (const float4*)sp + rb4;
    const float4* A4 = (const float4*)tq + rb4;
    const float4* B4 = (const float4*)tp + rb4;

    float4 qv[4], pv[4];
    float sq2 = 0.f, sp2 = 0.f, dq = 0.f, dp = 0.f, qp = 0.f;
    #pragma unroll
    for (int j = 0; j < 4; ++j) {
        const int idx = j * 64 + l;
        float4 q = Q4[idx], p = P4[idx], a = A4[idx], b = B4[idx];
        qv[j] = q; pv[j] = p;
        sq2 += q.x*q.x + q.y*q.y + q.z*q.z + q.w*q.w;
        sp2 += p.x*p.x + p.y*p.y + p.z*p.z + p.w*p.w;
        float dx = q.x-a.x, dy = q.y-a.y, dz = q.z-a.z, dw = q.w-a.w;
        dq += dx*dx + dy*dy + dz*dz + dw*dw;
        dx = p.x-b.x; dy = p.y-b.y; dz = p.z-b.z; dw = p.w-b.w;
        dp += dx*dx + dy*dy + dz*dz + dw*dw;
        qp += q.x*p.x + q.y*p.y + q.z*p.z + q.w*p.w;
    }

    #pragma unroll
    for (int m = 1; m <= 32; m <<= 1) {
        sq2 += __shfl_xor(sq2, m);
        sp2 += __shfl_xor(sp2, m);
        dq  += __shfl_xor(dq, m);
        dp  += __shfl_xor(dp, m);
        qp  += __shfl_xor(qp, m);
    }

    const float rq = 1.0f / fmaxf(sqrtf(sq2), 1e-8f);
    const float rp = 1.0f / fmaxf(sqrtf(sp2), 1e-8f);

    if (l == 0) {
        ppq[r] = dq;
        ppp[r] = dp;
        ppd[r] = qp * rq * rp;
    }

    const float fq = rq * FP8_SCALE;
    const float fp = rp * FP8_SCALE;
    int* qrow = qn + (size_t)r * (D_DIM / 4);
    int* prow = pn + (size_t)r * (D_DIM / 4);
    #pragma unroll
    for (int j = 0; j < 4; ++j) {
        const int idx = j * 64 + l;
        int pk = __builtin_amdgcn_cvt_pk_fp8_f32(qv[j].x * fq, qv[j].y * fq, 0, false);
        pk     = __builtin_amdgcn_cvt_pk_fp8_f32(qv[j].z * fq, qv[j].w * fq, pk, true);
        qrow[idx] = pk;
        pk = __builtin_amdgcn_cvt_pk_fp8_f32(pv[j].x * fp, pv[j].y * fp, 0, false);
        pk = __builtin_amdgcn_cvt_pk_fp8_f32(pv[j].z * fp, pv[j].w * fp, pk, true);
        prow[idx] = pk;
    }
}

// ---------------------------------------------------------------------------
// Kernel 2: S = Qn @ Pn^T via MX-scaled fp8 MFMA 16x16x128.
// *** 128x128 tile, 4 waves (2x2, 64x64 patch), single-buffer 32 KiB LDS,
//     3 blocks/CU (m97 cross-block-overlap regime) — the r8 best (76 us) ***
//
// Session verdict (r1-r9): one big lockstep block runs DS and MFMA in SUM
// (r1-r5 ~6100 cy/step regardless of schedule); bigger per-wave patches
// blow the register file (r7: spill, 3.5x hbm_bytes); B direct-from-L2 is
// a strided 16B gather that serializes the TA path (r4 lockstep, r9
// overlapped — both lose).  3 small blocks/CU overlapping one block's DS
// burst with another's MFMA burst is the only structural win (+7%).
// LDS-port floor for this config ~50 us; r8 runs at 76 us (~1.4x), with
// the 4.0 conflict-cy/b128 constant structural (b128 quarter-wave phasing,
// held across 4 address patterns — not swizzle-fixable).
//
// Per wave/step: 8 ds_read_b128 + 16 MFMA; acc 64 + frags 64 regs.
// r5 LDS swizzle (chunk = 2q^r7) on the global source address.
// ---------------------------------------------------------------------------
union Frag { int8v v8; struct { int4v lo, hi; } h; };

__global__ void __launch_bounds__(256, 3) gemm_rowsum_kernel(
    const u8* __restrict__ Q, const u8* __restrict__ P,
    float* __restrict__ gpart)
{
    __shared__ u8 smA[128 * 128];   // 16 KiB, row stride 128 B
    __shared__ u8 smB[128 * 128];   // 16 KiB   (total 32 KiB)

    const int tid  = threadIdx.x;
    const int wave = tid >> 6;         // 0..3
    const int lane = tid & 63;
    const int wm   = wave >> 1;        // 0..1 : 64-row half of the tile
    const int wn   = wave & 1;         // 0..1 : 64-col half of the tile
    const int bm   = blockIdx.y;
    const int bn   = blockIdx.x;

    // staging: one STAGE call (256 threads) covers 32 rows x 128 B.
    // LDS written linearly; 16B-chunk XOR swizzle (r5 scheme) applied on
    // the GLOBAL source address; read side XORs with row&7.
    const int srow   = tid >> 3;                    // 0..31 within a call
    const int schunk = (tid & 7) ^ (srow & 7);      // pre-swizzled 16B chunk
    const u8* Ag = Q + (size_t)(bm * 128 + srow) * D_DIM + schunk * 16;
    const u8* Bg = P + (size_t)(bn * 128 + srow) * D_DIM + schunk * 16;
    const int ldsw = wave * 1024;                   // wave's 8-row sub-chunk

#define STAGE_A(rbase, k0)                                                     \
    __builtin_amdgcn_global_load_lds(                                          \
        (const __attribute__((address_space(1))) void*)(Ag + (size_t)(rbase) * D_DIM + (k0)), \
        (__attribute__((address_space(3))) void*)(smA + (rbase) * 128 + ldsw), 16, 0, 0)
#define STAGE_B(rbase, k0)                                                     \
    __builtin_amdgcn_global_load_lds(                                          \
        (const __attribute__((address_space(1))) void*)(Bg + (size_t)(rbase) * D_DIM + (k0)), \
        (__attribute__((address_space(3))) void*)(smB + (rbase) * 128 + ldsw), 16, 0, 0)

// 8 vmem issues per call, covering the full 128-row A and B tiles
#define STAGE_ALL(k0)                                                          \
    STAGE_A(0, k0); STAGE_A(32, k0); STAGE_A(64, k0); STAGE_A(96, k0);         \
    STAGE_B(0, k0); STAGE_B(32, k0); STAGE_B(64, k0); STAGE_B(96, k0);

    // fragment addressing (r5 swizzle):
    // A frag (mi): row = wm*64 + mi*16 + rw; k-chunks 2q,2q+1 at slots ^r7
    const int quad = lane >> 4;
    const int rw   = lane & 15;
    const int r7   = lane & 7;
    const int off_lo = ((2 * quad) ^ r7) * 16;
    const int off_hi = ((2 * quad + 1) ^ r7) * 16;
    const int arow_base = (wm * 64 + rw) * 128;     // + mi*2048
    const int brow_base = (wn * 64 + rw) * 128;     // + ni*2048

    f32x4 acc[4][4];
    #pragma unroll
    for (int i = 0; i < 4; ++i)
        #pragma unroll
        for (int j = 0; j < 4; ++j)
            acc[i][j] = (f32x4){0.f, 0.f, 0.f, 0.f};

    // prologue: stage step 0
    STAGE_ALL(0)

#define SB0 __builtin_amdgcn_sched_barrier(0);

#define MFMA1(mi, ni)                                                          \
    acc[mi][ni] = __builtin_amdgcn_mfma_scale_f32_16x16x128_f8f6f4(            \
        af[mi].v8, bf[ni].v8, acc[mi][ni],                                     \
        0, 0, 0, 0x7f7f7f7f, 0, 0x7f7f7f7f);

#define KSTEP(t, DO_NEXT)                                                      \
  {                                                                            \
    Frag af[4], bf[4];                                                         \
    /* stage(t) landed (only our 8 loads outstanding) */                       \
    asm volatile("s_waitcnt vmcnt(0)" ::: "memory");                           \
    __builtin_amdgcn_s_barrier();                                              \
    SB0                                                                        \
    /* 16 b128 reads: lo group then hi group */                                \
    _Pragma("unroll")                                                          \
    for (int mi = 0; mi < 4; ++mi)                                             \
      af[mi].h.lo = *(const int4v*)(smA + arow_base + mi * 2048 + off_lo);     \
    _Pragma("unroll")                                                          \
    for (int ni = 0; ni < 4; ++ni)                                             \
      bf[ni].h.lo = *(const int4v*)(smB + brow_base + ni * 2048 + off_lo);     \
    SB0                                                                        \
    _Pragma("unroll")                                                          \
    for (int mi = 0; mi < 4; ++mi)                                             \
      af[mi].h.hi = *(const int4v*)(smA + arow_base + mi * 2048 + off_hi);     \
    _Pragma("unroll")                                                          \
    for (int ni = 0; ni < 4; ++ni)                                             \
      bf[ni].h.hi = *(const int4v*)(smB + brow_base + ni * 2048 + off_hi);     \
    asm volatile("s_waitcnt lgkmcnt(0)" ::: "memory");                         \
    SB0                                                                        \
    __builtin_amdgcn_s_barrier();   /* all waves done reading -> WAR safe */   \
    SB0                                                                        \
    /* restage for t+1 (async, retired at next entry), then 16 MFMAs */        \
    if (DO_NEXT) { STAGE_ALL(((t) + 1) * 128) }                                \
    __builtin_amdgcn_s_setprio(1);                                             \
    MFMA1(0, 0) MFMA1(0, 1) MFMA1(1, 0) MFMA1(1, 1)                            \
    MFMA1(0, 2) MFMA1(0, 3) MFMA1(1, 2) MFMA1(1, 3)                            \
    MFMA1(2, 0) MFMA1(2, 1) MFMA1(3, 0) MFMA1(3, 1)                            \
    MFMA1(2, 2) MFMA1(2, 3) MFMA1(3, 2) MFMA1(3, 3)                            \
    __builtin_amdgcn_s_setprio(0);                                             \
  }

    KSTEP(0, true)
    KSTEP(1, true)
    KSTEP(2, true)
    KSTEP(3, true)
    KSTEP(4, true)
    KSTEP(5, true)
    KSTEP(6, true)
    KSTEP(7, false)

#undef KSTEP
#undef MFMA1
#undef SB0
#undef STAGE_ALL
#undef STAGE_A
#undef STAGE_B

    // epilogue: per-row sum of exp over this wave's 64 columns.
    // C/D layout (shape-determined): col = lane&15, row = quad*4 + reg
    float esum[4][4];
    #pragma unroll
    for (int mi = 0; mi < 4; ++mi)
        #pragma unroll
        for (int r = 0; r < 4; ++r) {
            float s = 0.f;
            #pragma unroll
            for (int ni = 0; ni < 4; ++ni)
                s += __expf(acc[mi][ni][r] * ACC_UNSCALE);
            esum[mi][r] = s;
        }
    #pragma unroll
    for (int m = 1; m <= 8; m <<= 1)
        #pragma unroll
        for (int mi = 0; mi < 4; ++mi)
            #pragma unroll
            for (int r = 0; r < 4; ++r)
                esum[mi][r] += __shfl_xor(esum[mi][r], m);

    // slice index = global_col / 64 = bn*2 + wn
    if (rw == 0) {
        float* dst = gpart + (size_t)(bn * 2 + wn) * B_ROWS
                   + bm * 128 + wm * 64;
        #pragma unroll
        for (int mi = 0; mi < 4; ++mi)
            #pragma unroll
            for (int r = 0; r < 4; ++r)
                dst[mi * 16 + quad * 4 + r] = esum[mi][r];
    }
}

// ---------------------------------------------------------------------------
// Kernel 3: per-row sum of 128 gpart slices -> log; fold in the three
// pp-array reductions; one float4 partial per block. (unchanged)
// ---------------------------------------------------------------------------
__global__ void __launch_bounds__(256) reduce_kernel(
    const float* __restrict__ gpart,
    const float* __restrict__ ppq, const float* __restrict__ ppp,
    const float* __restrict__ ppd, float4* __restrict__ bpart)
{
    const int t = threadIdx.x;
    const int r = blockIdx.x * 256 + t;
    float s = 0.f;
    #pragma unroll 8
    for (int j = 0; j < 128; ++j) s += gpart[(size_t)j * B_ROWS + r];
    float ls = logf(s);
    float v2 = ppq[r], v3 = ppp[r], v4 = ppd[r];
    #pragma unroll
    for (int m = 1; m <= 32; m <<= 1) {
        ls += __shfl_xor(ls, m);
        v2 += __shfl_xor(v2, m);
        v3 += __shfl_xor(v3, m);
        v4 += __shfl_xor(v4, m);
    }
    __shared__ float red[4][4];
    if ((t & 63) == 0) {
        red[t >> 6][0] = ls; red[t >> 6][1] = v2;
        red[t >> 6][2] = v3; red[t >> 6][3] = v4;
    }
    __syncthreads();
    if (t == 0) {
        float4 o;
        o.x = red[0][0] + red[1][0] + red[2][0] + red[3][0];
        o.y = red[0][1] + red[1][1] + red[2][1] + red[3][1];
        o.z = red[0][2] + red[1][2] + red[2][2] + red[3][2];
        o.w = red[0][3] + red[1][3] + red[2][3] + red[3][3];
        bpart[blockIdx.x] = o;
    }
}

// ---------------------------------------------------------------------------
// Kernel 4: final scalar combine (1 wave, 32 float4 partials) (unchanged)
// ---------------------------------------------------------------------------
__global__ void __launch_bounds__(64) finalize_kernel(
    const float4* __restrict__ bpart, float* __restrict__ out)
{
    const int t = threadIdx.x;
    float4 v = (t < 32) ? bpart[t] : (float4){0.f, 0.f, 0.f, 0.f};
    #pragma unroll
    for (int m = 1; m <= 16; m <<= 1) {
        v.x += __shfl_xor(v.x, m);
        v.y += __shfl_xor(v.y, m);
        v.z += __shfl_xor(v.z, m);
        v.w += __shfl_xor(v.w, m);
    }
    if (t == 0) {
        const float inv_bd = 1.0f / ((float)B_ROWS * (float)D_DIM);
        float distill   = 0.5f * (v.y + v.z) * inv_bd;
        float retrieval = (v.x - v.w) / (float)B_ROWS;
        out[0] = 0.5f * distill + 0.5f * retrieval;
    }
}

extern "C" void kernel_launch(void* const* d_in, const int* in_sizes, int n_in,
                              void* d_out, int out_size, void* d_ws, size_t ws_size,
                              hipStream_t stream) {
    const float* sq = (const float*)d_in[0];
    const float* sp = (const float*)d_in[1];
    const float* tq = (const float*)d_in[2];
    const float* tp = (const float*)d_in[3];

    char* ws = (char*)d_ws;
    float*  ppq   = (float*)(ws);
    float*  ppp   = (float*)(ws + 32768);
    float*  ppd   = (float*)(ws + 65536);
    float4* bpart = (float4*)(ws + 98304);
    float*  gpart = (float*)(ws + 131072);                        // 4 MiB
    int*    qn    = (int*)(ws + 131072 + (size_t)128 * B_ROWS * 4);
    int*    pn    = (int*)((char*)qn + (size_t)B_ROWS * D_DIM);

    prep_kernel<<<B_ROWS / 4, 256, 0, stream>>>(sq, sp, tq, tp, qn, pn, ppq, ppp, ppd);
    gemm_rowsum_kernel<<<dim3(64, 64), 256, 0, stream>>>((const u8*)qn, (const u8*)pn, gpart);
    reduce_kernel<<<32, 256, 0, stream>>>(gpart, ppq, ppp, ppd, bpart);
    finalize_kernel<<<1, 64, 0, stream>>>(bpart, (float*)d_out);
}